// Round 6
// baseline (215.632 us; speedup 1.0000x reference)
//
#include <hip/hip_runtime.h>

// SSIM loss, fused. R11: register+shuffle kernel — ZERO LDS, ZERO barriers.
// R10 post-mortem: fixing occupancy quantization (27->35%) bought only 3us;
// all pipes <=35% busy -> the LDS-staged S/Q exchange + per-row barrier
// drain IS the bottleneck structure, not residency.
// R11: one wave owns a full 512-col x STRIP=8 row strip; lane owns 8
// adjacent cols (2 float4 loads per image). Column sums cs[4][8] live in
// registers. 11-tap horizontal window = local prefix/suffix sums + 5
// suffix sums from lane t-1 (shfl_up) + 5 prefix sums from lane t+1
// (shfl_down); image edges folded in via mask-fma (mL/mR zero the
// out-of-range shuffles). 10 bpermutes/ch/row replaces 5 ds_reads/px/ch +
// all ds_writes + all barriers of R5-R10.
//  - u=x+y, v=x-y -> Su,Sv,Suu,Svv channel reduction (proven R5-R10).
//  - no __shared__ at all -> no barrier, no vmcnt(0)/lgkmcnt(0) drains.
//  - STRIP=8 -> 4096 waves = 16 waves/CU; __launch_bounds__(64,2) = 128
//    VGPR cap (R8-proven to fit ~128-reg working sets, zero spill).
//  - add-row prefetched one iteration ahead (cover = full SSIM row);
//    sub-row issued before SSIM math (L2-resident: fetched 11 rows ago).
// NOTE: horizontal summation order differs from R5-R10 -> absmax expected
// ~1e-7 (first nonzero of the session), well within tolerance.

#define IMG_H 512
#define IMG_W 512
#define N_IMG 64
#define STRIP 8            // output rows per wave -> grid (64,64)=4096 waves
#define NTHREADS 64        // one wave per block

__global__ __launch_bounds__(NTHREADS, 2) void ssim_kernel(const float* __restrict__ img1,
                                                           const float* __restrict__ img2,
                                                           float* __restrict__ ws) {
    const int t = threadIdx.x;                   // lane 0..63
    const int b = blockIdx.y;
    const int r0 = blockIdx.x * STRIP;
    const float* __restrict__ p1 = img1 + (size_t)b * (IMG_H * IMG_W);
    const float* __restrict__ p2 = img2 + (size_t)b * (IMG_H * IMG_W);
    const int c8 = 8 * t;                        // lane owns cols c8..c8+7

    float cs[4][8];                              // ch: u, v, uu, vv
#pragma unroll
    for (int ch = 0; ch < 4; ++ch)
#pragma unroll
        for (int j = 0; j < 8; ++j) cs[ch][j] = 0.0f;

    auto addR = [&](float4 xa, float4 xb, float4 ya, float4 yb) {
        float xs[8] = {xa.x, xa.y, xa.z, xa.w, xb.x, xb.y, xb.z, xb.w};
        float ys[8] = {ya.x, ya.y, ya.z, ya.w, yb.x, yb.y, yb.z, yb.w};
#pragma unroll
        for (int j = 0; j < 8; ++j) {
            float u = xs[j] + ys[j], v = xs[j] - ys[j];
            cs[0][j] += u;                   cs[1][j] += v;
            cs[2][j] = fmaf(u, u, cs[2][j]); cs[3][j] = fmaf(v, v, cs[3][j]);
        }
    };
    auto subR = [&](float4 xa, float4 xb, float4 ya, float4 yb) {
        float xs[8] = {xa.x, xa.y, xa.z, xa.w, xb.x, xb.y, xb.z, xb.w};
        float ys[8] = {ya.x, ya.y, ya.z, ya.w, yb.x, yb.y, yb.z, yb.w};
#pragma unroll
        for (int j = 0; j < 8; ++j) {
            float u = xs[j] + ys[j], v = xs[j] - ys[j];
            cs[0][j] -= u;                    cs[1][j] -= v;
            cs[2][j] = fmaf(-u, u, cs[2][j]); cs[3][j] = fmaf(-v, v, cs[3][j]);
        }
    };

    // Warm vertical window for output row r0 (zero pad above the image).
    {
        int rlo = r0 - 5; if (rlo < 0) rlo = 0;
        const int rhi = r0 + 5;                  // r0 <= 504 -> rhi <= 509
        for (int r = rlo; r <= rhi; ++r) {
            const float* a1 = p1 + (size_t)r * IMG_W + c8;
            const float* a2 = p2 + (size_t)r * IMG_W + c8;
            addR(*(const float4*)a1, *(const float4*)(a1 + 4),
                 *(const float4*)a2, *(const float4*)(a2 + 4));
        }
    }

    // Prefetched add-row (row rn+5, clamped; consume guard applies bounds).
    float4 fxa, fxb, fya, fyb;
    auto prefetchAdd = [&](int rn) {
        int ra = rn + 5; if (ra > IMG_H - 1) ra = IMG_H - 1;
        const float* a1 = p1 + (size_t)ra * IMG_W + c8;
        const float* a2 = p2 + (size_t)ra * IMG_W + c8;
        fxa = *(const float4*)a1; fxb = *(const float4*)(a1 + 4);
        fya = *(const float4*)a2; fyb = *(const float4*)(a2 + 4);
    };

    const float mL = (t > 0)  ? 1.0f : 0.0f;     // zero shfl_up at lane 0
    const float mR = (t < 63) ? 1.0f : 0.0f;     // zero shfl_down at lane 63
    constexpr float inv  = 1.0f / 121.0f;
    constexpr float inv2 = 0.5f / 121.0f;
    constexpr float C1c = 0.01f * 0.01f;
    constexpr float C2c = 0.03f * 0.03f;
    float acc = 0.0f;

    prefetchAdd(r0 + 1);

    for (int i = 0; i < STRIP; ++i) {
        // --- horizontal 11-tap windows for row r0+i, all in registers ---
        float W[4][8];
#pragma unroll
        for (int ch = 0; ch < 4; ++ch) {
            float s0 = cs[ch][0], s1 = cs[ch][1], s2 = cs[ch][2], s3 = cs[ch][3];
            float s4 = cs[ch][4], s5 = cs[ch][5], s6 = cs[ch][6], s7 = cs[ch][7];
            float P2 = s0 + s1, P3 = P2 + s2, P4 = P3 + s3, P5 = P4 + s4;
            float P6 = P5 + s5, P7 = P6 + s6, P8 = P7 + s7;
            float Q2 = s7 + s6, Q3 = Q2 + s5, Q4 = Q3 + s4, Q5 = Q4 + s3;
            // from left neighbor: its suffix sums (cols 8t-5..8t-1 etc.)
            float Lq1 = __shfl_up(s7, 1), Lq2 = __shfl_up(Q2, 1),
                  Lq3 = __shfl_up(Q3, 1), Lq4 = __shfl_up(Q4, 1),
                  Lq5 = __shfl_up(Q5, 1);
            // from right neighbor: its prefix sums (cols 8t+8.. etc.)
            float Rp1 = __shfl_down(s0, 1), Rp2 = __shfl_down(P2, 1),
                  Rp3 = __shfl_down(P3, 1), Rp4 = __shfl_down(P4, 1),
                  Rp5 = __shfl_down(P5, 1);
            W[ch][0] = fmaf(Lq5, mL, P6);                    // cols 8t-5..8t+5
            W[ch][1] = fmaf(Lq4, mL, P7);
            W[ch][2] = fmaf(Lq3, mL, P8);
            W[ch][3] = fmaf(Rp1, mR, fmaf(Lq2, mL, P8));
            W[ch][4] = fmaf(Rp2, mR, fmaf(Lq1, mL, P8));
            W[ch][5] = fmaf(Rp3, mR, P8);
            W[ch][6] = fmaf(Rp4, mR, P8 - s0);
            W[ch][7] = fmaf(Rp5, mR, P8 - P2);               // cols 8t+2..8t+12
        }

        // Issue sub-row loads now (L2-resident: same rows fetched 11 rows
        // ago); SSIM math below covers their latency.
        const int rn = r0 + i + 1;
        const bool last = (i == STRIP - 1);
        const bool doSub = !last && (rn - 6 >= 0);           // wave-uniform
        float4 sxa, sxb, sya, syb;
        if (doSub) {
            const float* a1 = p1 + (size_t)(rn - 6) * IMG_W + c8;
            const float* a2 = p2 + (size_t)(rn - 6) * IMG_W + c8;
            sxa = *(const float4*)a1; sxb = *(const float4*)(a1 + 4);
            sya = *(const float4*)a2; syb = *(const float4*)(a2 + 4);
        }

        // --- SSIM for the 8 pixels this lane owns in row r0+i ---
#pragma unroll
        for (int j = 0; j < 8; ++j) {
            float mu_u = W[0][j] * inv, mu_v = W[1][j] * inv;
            float uu = mu_u * mu_u, vv = mu_v * mu_v;
            float Pq = 0.5f * (uu + vv);                    // mu1^2 + mu2^2
            float Mq = 0.5f * (uu - vv);                    // 2*mu1*mu2
            float A = fmaf(W[2][j] + W[3][j], inv2, -Pq);   // sig1^2+sig2^2
            float B = fmaf(W[2][j] - W[3][j], inv2, -Mq);   // 2*sig12
            acc += __fdividef((Mq + C1c) * (B + C2c), (Pq + C1c) * (A + C2c));
        }

        // --- advance vertical window to row rn (tail; wave-uniform) ---
        if (!last) {
            if (rn + 5 < IMG_H) addR(fxa, fxb, fya, fyb);   // prefetched 1 iter ago
            if (doSub)          subR(sxa, sxb, sya, syb);
            if (i < STRIP - 2)  prefetchAdd(rn + 1);        // in flight across
        }                                                   // next row's SSIM
    }

    // Reduce: intra-wave shuffle tree -> one atomic per wave.
#pragma unroll
    for (int off = 32; off > 0; off >>= 1) acc += __shfl_down(acc, off);
    if (t == 0) atomicAdd(ws, acc);
}

__global__ void ssim_finalize(const float* __restrict__ ws, float* __restrict__ out) {
    constexpr float inv_n = 1.0f / (float)((size_t)N_IMG * IMG_H * IMG_W);
    out[0] = 1.0f - ws[0] * inv_n;
}

extern "C" void kernel_launch(void* const* d_in, const int* in_sizes, int n_in,
                              void* d_out, int out_size, void* d_ws, size_t ws_size,
                              hipStream_t stream) {
    const float* img1 = (const float*)d_in[0];
    const float* img2 = (const float*)d_in[1];
    float* out = (float*)d_out;
    float* ws = (float*)d_ws;

    hipMemsetAsync(ws, 0, sizeof(float), stream);

    dim3 grid(IMG_H / STRIP, N_IMG);   // (64, 64) = 4096 blocks, 1 wave each
    ssim_kernel<<<grid, NTHREADS, 0, stream>>>(img1, img2, ws);
    ssim_finalize<<<1, 1, 0, stream>>>(ws, out);
}